// Round 1
// baseline (177.934 us; speedup 1.0000x reference)
//
#include <hip/hip_runtime.h>

// LSTM_WP: B=4096 batch-1 LSTMs, T=H=128, input_size=1, fused MFMA-f16 recurrence.
// One block = 16 batches, 512 threads (8 waves). Wave w owns gate columns
// j in [16w, 16w+16) for all 4 gate groups -> lane-local c/h update.
// W_hh held in registers as MFMA B-fragments (f16); h double-buffered in LDS.

#define H   128
#define T   128
#define MB  16          // batches per block
#define BLOCK 512
#define HSTRIDE 136     // f16 per h row: 272 B (16B aligned), ~2-way banks

typedef _Float16 f16x8 __attribute__((ext_vector_type(8)));
typedef float    f32x4 __attribute__((ext_vector_type(4)));

__device__ __forceinline__ float fsig(float v) {
    // sigmoid(v) = 1/(1+exp(-v)); native exp+rcp (~1 ulp each, plenty for 1.9e-3 budget)
    float e = __expf(-v);
    return __builtin_amdgcn_rcpf(1.0f + e);
}
__device__ __forceinline__ float ftanh(float v) {
    // tanh(v) = 1 - 2/(1+exp(2v)); saturates correctly at +/-inf via rcp(inf)=0
    float e = __expf(2.0f * v);
    return 1.0f - 2.0f * __builtin_amdgcn_rcpf(1.0f + e);
}

__launch_bounds__(BLOCK, 2)
__global__ void lstm_fused_kernel(const float* __restrict__ x,
                                  const float* __restrict__ W_ih,
                                  const float* __restrict__ W_hh,
                                  const float* __restrict__ b_ih,
                                  const float* __restrict__ b_hh,
                                  const float* __restrict__ fc_W,
                                  const float* __restrict__ fc_b,
                                  float* __restrict__ out)
{
    __shared__ float xs[MB][T];                                  // 8 KB input tile
    __shared__ __align__(16) _Float16 hbuf[2][MB][HSTRIDE];      // 8.5 KB h double-buffer

    const int tid  = threadIdx.x;
    const int wave = tid >> 6;
    const int lane = tid & 63;
    const int l15  = lane & 15;
    const int q    = lane >> 4;            // 0..3
    const int jcol = wave * 16 + l15;      // this lane's hidden column, 0..127

    // ---- stage x tile: 16 batches x 128 t, coalesced float4 (512 x 16B = 8 KB) ----
    {
        const float4* src = (const float4*)(x + (size_t)blockIdx.x * (MB * T));
        float4* dst = (float4*)(&xs[0][0]);
        dst[tid] = src[tid];
    }
    // zero the t=0 read buffer (h0 = 0)
    for (int i = tid; i < MB * HSTRIDE; i += BLOCK)
        (&hbuf[0][0][0])[i] = (_Float16)0.0f;

    // ---- preload W_hh B-fragments + (W_ih, b_ih+b_hh) for this lane's 4 gate rows ----
    // B-fragment layout (16x16x32): n = lane&15 (16 rows of W_hh), k = q*8 + i, contiguous.
    f16x8 wf[4][4];            // [gate group][k chunk]
    float wih[4], bias[4];
    #pragma unroll
    for (int g = 0; g < 4; ++g) {
        const int n = g * H + jcol;        // global gate index (i,f,g,o blocks of 128)
        wih[g]  = W_ih[n];
        bias[g] = b_ih[n] + b_hh[n];
        #pragma unroll
        for (int kc = 0; kc < 4; ++kc) {
            const float* wp = W_hh + (size_t)n * H + kc * 32 + q * 8;
            float4 w0 = ((const float4*)wp)[0];
            float4 w1 = ((const float4*)wp)[1];
            f16x8 f;
            f[0] = (_Float16)w0.x; f[1] = (_Float16)w0.y;
            f[2] = (_Float16)w0.z; f[3] = (_Float16)w0.w;
            f[4] = (_Float16)w1.x; f[5] = (_Float16)w1.y;
            f[6] = (_Float16)w1.z; f[7] = (_Float16)w1.w;
            wf[g][kc] = f;
        }
    }

    float c[4] = {0.f, 0.f, 0.f, 0.f};     // cell state, fp32, lane-local

    __syncthreads();

    for (int t = 0; t < T; ++t) {
        const int rb = t & 1;              // read h(t-1) from here
        const int wb = rb ^ 1;             // write h(t) here

        // A-fragments: m(batch) = lane&15, k = kc*32 + q*8 + i (contiguous f16)
        f16x8 af[4];
        #pragma unroll
        for (int kc = 0; kc < 4; ++kc)
            af[kc] = *(const f16x8*)&hbuf[rb][l15][kc * 32 + q * 8];

        // acc init = gate pre-activations: x[b][t]*W_ih[n] + (b_ih+b_hh)[n]
        f32x4 acc[4];
        #pragma unroll
        for (int g = 0; g < 4; ++g) {
            #pragma unroll
            for (int r = 0; r < 4; ++r) {
                const int b = q * 4 + r;   // C-layout row = quad*4 + reg
                acc[g][r] = xs[b][t] * wih[g] + bias[g];
            }
        }

        // gates += h @ W_hh^T  (4 k-chunks x 4 gate tiles, independent acc chains)
        #pragma unroll
        for (int kc = 0; kc < 4; ++kc) {
            #pragma unroll
            for (int g = 0; g < 4; ++g)
                acc[g] = __builtin_amdgcn_mfma_f32_16x16x32_f16(af[kc], wf[g][kc], acc[g], 0, 0, 0);
        }

        // lane-local elementwise LSTM update; h(t) -> LDS as f16
        #pragma unroll
        for (int r = 0; r < 4; ++r) {
            const int b = q * 4 + r;
            float ig = fsig(acc[0][r]);
            float fg = fsig(acc[1][r]);
            float gg = ftanh(acc[2][r]);
            float og = fsig(acc[3][r]);
            float cn = fg * c[r] + ig * gg;
            c[r] = cn;
            float hv = og * ftanh(cn);
            hbuf[wb][b][jcol] = (_Float16)hv;
        }
        __syncthreads();
    }

    // ---- epilogue: out[b] = fc_b + sum_j fc_W[j] * hT[b][j] ----
    // final h is in hbuf[(T)&1 == 0]. 16 threads per batch, shfl-reduce width 16.
    if (tid < 256) {
        const int b    = tid >> 4;
        const int part = tid & 15;
        const _Float16* hrow = &hbuf[0][b][0];
        float s = 0.0f;
        #pragma unroll
        for (int i = 0; i < 8; ++i) {
            const int j = part * 8 + i;
            s += fc_W[j] * (float)hrow[j];
        }
        s += __shfl_xor(s, 8, 16);
        s += __shfl_xor(s, 4, 16);
        s += __shfl_xor(s, 2, 16);
        s += __shfl_xor(s, 1, 16);
        if (part == 0)
            out[blockIdx.x * MB + b] = s + fc_b[0];
    }
}

extern "C" void kernel_launch(void* const* d_in, const int* in_sizes, int n_in,
                              void* d_out, int out_size, void* d_ws, size_t ws_size,
                              hipStream_t stream)
{
    const float* x    = (const float*)d_in[0];
    const float* W_ih = (const float*)d_in[1];
    const float* W_hh = (const float*)d_in[2];
    const float* b_ih = (const float*)d_in[3];
    const float* b_hh = (const float*)d_in[4];
    const float* fc_W = (const float*)d_in[5];
    const float* fc_b = (const float*)d_in[6];
    float* out = (float*)d_out;

    const int B = in_sizes[0] / H;         // 4096 chunks
    dim3 grid(B / MB);                     // 256 blocks -> 1 per CU
    dim3 block(BLOCK);                     // 8 waves -> 2 per SIMD
    hipLaunchKernelGGL(lstm_fused_kernel, grid, block, 0, stream,
                       x, W_ih, W_hh, b_ih, b_hh, fc_W, fc_b, out);
}